// Round 1
// baseline (1549.368 us; speedup 1.0000x reference)
//
#include <hip/hip_runtime.h>

#define N_NODES 100000
#define IN_F 256
#define OUT_F 128

// ---------------------------------------------------------------------------
// support = x @ W   (fp32, vector ALU — no fp32 MFMA on CDNA4)
// 32 rows/block, 256 threads, each thread computes 4 rows x 4 cols.
// K staged through LDS in chunks of 64.
// ---------------------------------------------------------------------------
__global__ __launch_bounds__(256) void gemm_kernel(
    const float* __restrict__ x, const float* __restrict__ w,
    float* __restrict__ sup) {
  __shared__ float Xs[32][65];     // +1 pad breaks stride-64 conflicts
  __shared__ float Ws[64][OUT_F];

  const int tid = threadIdx.x;
  const int row0 = blockIdx.x * 32;      // N_NODES % 32 == 0 -> no bounds checks
  const int tx = tid & 31;               // col group: cols tx*4 .. tx*4+3
  const int ty = tid >> 5;               // row group: rows ty*4 .. ty*4+3

  float acc[4][4] = {{0.f, 0.f, 0.f, 0.f}};

  for (int kk = 0; kk < IN_F; kk += 64) {
    // stage X tile: 32 x 64 (coalesced: consecutive tid -> consecutive k)
#pragma unroll
    for (int i = 0; i < 8; ++i) {
      const int idx = tid + i * 256;
      const int r = idx >> 6, k = idx & 63;
      Xs[r][k] = x[(row0 + r) * IN_F + kk + k];
    }
    // stage W tile: 64 x 128 (coalesced)
#pragma unroll
    for (int i = 0; i < 32; ++i) {
      const int idx = tid + i * 256;
      const int k = idx >> 7, c = idx & 127;
      Ws[k][c] = w[(kk + k) * OUT_F + c];
    }
    __syncthreads();

#pragma unroll 8
    for (int k = 0; k < 64; ++k) {
      const float4 wb = *(const float4*)&Ws[k][tx * 4];  // ds_read_b128
#pragma unroll
      for (int j = 0; j < 4; ++j) {
        const float xa = Xs[ty * 4 + j][k];  // broadcast across tx lanes
        acc[j][0] = fmaf(xa, wb.x, acc[j][0]);
        acc[j][1] = fmaf(xa, wb.y, acc[j][1]);
        acc[j][2] = fmaf(xa, wb.z, acc[j][2]);
        acc[j][3] = fmaf(xa, wb.w, acc[j][3]);
      }
    }
    __syncthreads();
  }

#pragma unroll
  for (int j = 0; j < 4; ++j) {
    const int gr = row0 + ty * 4 + j;
    const float4 v = make_float4(acc[j][0], acc[j][1], acc[j][2], acc[j][3]);
    *(float4*)&sup[gr * OUT_F + tx * 4] = v;  // coalesced 16B store
  }
}

// ---------------------------------------------------------------------------
// out[n][f] = bias[f]  (vectorized float4 broadcast init)
// ---------------------------------------------------------------------------
__global__ __launch_bounds__(256) void bias_init_kernel(
    float* __restrict__ out, const float* __restrict__ bias) {
  const int t = blockIdx.x * blockDim.x + threadIdx.x;
  const int idx = t * 4;                        // grid sized exactly
  *(float4*)(out + idx) = *(const float4*)(bias + (idx & (OUT_F - 1)));
}

// ---------------------------------------------------------------------------
// COO scatter: one wave (64 lanes) per edge, 2 features per lane.
// out[row[e]][:] += support[col[e]][:] * ew[e]   via float atomics.
// ---------------------------------------------------------------------------
__global__ __launch_bounds__(256) void scatter_kernel(
    const float* __restrict__ sup, const float* __restrict__ ew,
    const int* __restrict__ row, const int* __restrict__ col,
    float* __restrict__ out, int E) {
  const long long t = (long long)blockIdx.x * blockDim.x + threadIdx.x;
  const int e = (int)(t >> 6);
  if (e >= E) return;
  const int lane = (int)(t & 63);

  const int c = col[e];          // same addr across wave -> broadcast load
  const int r = row[e];
  const float wv = ew[e];

  const float2 s = *(const float2*)(sup + (long long)c * OUT_F + lane * 2);
  float* o = out + (long long)r * OUT_F + lane * 2;
  atomicAdd(o, s.x * wv);
  atomicAdd(o + 1, s.y * wv);
}

extern "C" void kernel_launch(void* const* d_in, const int* in_sizes, int n_in,
                              void* d_out, int out_size, void* d_ws, size_t ws_size,
                              hipStream_t stream) {
  const float* x = (const float*)d_in[0];
  const float* weight = (const float*)d_in[1];
  const float* bias = (const float*)d_in[2];
  const float* edge_weight = (const float*)d_in[3];
  const int* row = (const int*)d_in[4];
  const int* col = (const int*)d_in[5];
  float* out = (float*)d_out;
  float* sup = (float*)d_ws;    // N_NODES * OUT_F floats = 51.2 MB
  const int E = in_sizes[3];

  gemm_kernel<<<N_NODES / 32, 256, 0, stream>>>(x, weight, sup);
  bias_init_kernel<<<(N_NODES * OUT_F / 4) / 256, 256, 0, stream>>>(out, bias);
  scatter_kernel<<<(int)(((long long)E * 64 + 255) / 256), 256, 0, stream>>>(
      sup, edge_weight, row, col, out, E);
}

// Round 2
// 815.862 us; speedup vs baseline: 1.8991x; 1.8991x over previous
//
#include <hip/hip_runtime.h>

#define N_NODES 100000
#define IN_F 256
#define OUT_F 128

// ---------------------------------------------------------------------------
// ws layout (bytes):
//   sup     [         0,  51,200,000)  float  [N, OUT_F]
//   ebuf    [51,200,000,  64,000,000)  int2   [E]  {col, bits(edge_weight)}
//   offsets [64,000,000,  64,400,004)  int    [N+1]
//   cursor  [64,400,008,  64,800,008)  int    [N]
//   counts  [64,800,016,  65,200,016)  int    [N]
// ---------------------------------------------------------------------------
#define WS_SUP 0
#define WS_EBUF 51200000
#define WS_OFFS 64000000
#define WS_CURS 64400008
#define WS_CNTS 64800016
#define WS_NEEDED 65200016

// ---------------------------------------------------------------------------
// support = x @ W   (fp32, vector ALU — no fp32 MFMA on CDNA4)
// ---------------------------------------------------------------------------
__global__ __launch_bounds__(256) void gemm_kernel(
    const float* __restrict__ x, const float* __restrict__ w,
    float* __restrict__ sup) {
  __shared__ float Xs[32][65];
  __shared__ float Ws[64][OUT_F];

  const int tid = threadIdx.x;
  const int row0 = blockIdx.x * 32;
  const int tx = tid & 31;
  const int ty = tid >> 5;

  float acc[4][4] = {{0.f, 0.f, 0.f, 0.f}};

  for (int kk = 0; kk < IN_F; kk += 64) {
#pragma unroll
    for (int i = 0; i < 8; ++i) {
      const int idx = tid + i * 256;
      const int r = idx >> 6, k = idx & 63;
      Xs[r][k] = x[(row0 + r) * IN_F + kk + k];
    }
#pragma unroll
    for (int i = 0; i < 32; ++i) {
      const int idx = tid + i * 256;
      const int k = idx >> 7, c = idx & 127;
      Ws[k][c] = w[(kk + k) * OUT_F + c];
    }
    __syncthreads();

#pragma unroll 8
    for (int k = 0; k < 64; ++k) {
      const float4 wb = *(const float4*)&Ws[k][tx * 4];
#pragma unroll
      for (int j = 0; j < 4; ++j) {
        const float xa = Xs[ty * 4 + j][k];
        acc[j][0] = fmaf(xa, wb.x, acc[j][0]);
        acc[j][1] = fmaf(xa, wb.y, acc[j][1]);
        acc[j][2] = fmaf(xa, wb.z, acc[j][2]);
        acc[j][3] = fmaf(xa, wb.w, acc[j][3]);
      }
    }
    __syncthreads();
  }

#pragma unroll
  for (int j = 0; j < 4; ++j) {
    const int gr = row0 + ty * 4 + j;
    *(float4*)&sup[gr * OUT_F + tx * 4] =
        make_float4(acc[j][0], acc[j][1], acc[j][2], acc[j][3]);
  }
}

// ---------------------------------------------------------------------------
// CSR build: zero counts -> histogram -> scan -> bucket fill
// ---------------------------------------------------------------------------
__global__ __launch_bounds__(256) void zero_counts_kernel(int* __restrict__ counts) {
  const int i = blockIdx.x * 256 + threadIdx.x;
  if (i < N_NODES) counts[i] = 0;
}

__global__ __launch_bounds__(256) void hist_kernel(
    const int* __restrict__ row, int* __restrict__ counts, int E) {
  const int e = blockIdx.x * 256 + threadIdx.x;
  if (e < E) atomicAdd(&counts[row[e]], 1);
}

// Single-block exclusive scan over N_NODES counts (1024 threads, 98 elems each).
__global__ __launch_bounds__(1024) void scan_kernel(
    const int* __restrict__ counts, int* __restrict__ offsets,
    int* __restrict__ cursor) {
  __shared__ int s[1024];
  const int t = threadIdx.x;
  const int CH = (N_NODES + 1023) / 1024;  // 98
  const int start = t * CH;
  const int end = min(start + CH, N_NODES);

  int sum = 0;
  for (int i = start; i < end; ++i) sum += counts[i];
  s[t] = sum;
  __syncthreads();
  for (int off = 1; off < 1024; off <<= 1) {
    const int v = (t >= off) ? s[t - off] : 0;
    __syncthreads();
    s[t] += v;
    __syncthreads();
  }
  int base = (t == 0) ? 0 : s[t - 1];
  for (int i = start; i < end; ++i) {
    offsets[i] = base;
    cursor[i] = base;
    base += counts[i];
  }
  if (t == 1023) offsets[N_NODES] = s[1023];
}

__global__ __launch_bounds__(256) void fill_kernel(
    const int* __restrict__ row, const int* __restrict__ col,
    const float* __restrict__ ew, int* __restrict__ cursor,
    int2* __restrict__ ebuf, int E) {
  const int e = blockIdx.x * 256 + threadIdx.x;
  if (e >= E) return;
  const int pos = atomicAdd(&cursor[row[e]], 1);
  ebuf[pos] = make_int2(col[e], __float_as_int(ew[e]));
}

// ---------------------------------------------------------------------------
// Gather: one wave per destination node, 2 features/lane, no atomics.
// out[n][:] = sum_{e in CSR[n]} sup[col_e][:] * w_e + bias
// ---------------------------------------------------------------------------
__global__ __launch_bounds__(256) void gather_kernel(
    const float* __restrict__ sup, const int2* __restrict__ ebuf,
    const int* __restrict__ offsets, const float* __restrict__ bias,
    float* __restrict__ out) {
  const int wave = (int)((blockIdx.x * 256 + threadIdx.x) >> 6);
  const int lane = threadIdx.x & 63;
  if (wave >= N_NODES) return;

  const int start = offsets[wave];
  const int end = offsets[wave + 1];

  float a0 = 0.f, a1 = 0.f;
  for (int j = start; j < end; ++j) {
    const int2 e = ebuf[j];                     // wave-uniform 8B load
    const float w = __int_as_float(e.y);
    const float2 s =
        *(const float2*)(sup + (long long)e.x * OUT_F + lane * 2);  // 512B/wave coalesced
    a0 = fmaf(s.x, w, a0);
    a1 = fmaf(s.y, w, a1);
  }
  const float2 b = *(const float2*)(bias + lane * 2);
  *(float2*)(out + (long long)wave * OUT_F + lane * 2) =
      make_float2(a0 + b.x, a1 + b.y);
}

// ---------------------------------------------------------------------------
// Fallback (ws too small): bias init + atomic scatter (round-1 path)
// ---------------------------------------------------------------------------
__global__ __launch_bounds__(256) void bias_init_kernel(
    float* __restrict__ out, const float* __restrict__ bias) {
  const int t = blockIdx.x * blockDim.x + threadIdx.x;
  const int idx = t * 4;
  *(float4*)(out + idx) = *(const float4*)(bias + (idx & (OUT_F - 1)));
}

__global__ __launch_bounds__(256) void scatter_kernel(
    const float* __restrict__ sup, const float* __restrict__ ew,
    const int* __restrict__ row, const int* __restrict__ col,
    float* __restrict__ out, int E) {
  const long long t = (long long)blockIdx.x * blockDim.x + threadIdx.x;
  const int e = (int)(t >> 6);
  if (e >= E) return;
  const int lane = (int)(t & 63);
  const int c = col[e];
  const int r = row[e];
  const float wv = ew[e];
  const float2 s = *(const float2*)(sup + (long long)c * OUT_F + lane * 2);
  float* o = out + (long long)r * OUT_F + lane * 2;
  atomicAdd(o, s.x * wv);
  atomicAdd(o + 1, s.y * wv);
}

extern "C" void kernel_launch(void* const* d_in, const int* in_sizes, int n_in,
                              void* d_out, int out_size, void* d_ws, size_t ws_size,
                              hipStream_t stream) {
  const float* x = (const float*)d_in[0];
  const float* weight = (const float*)d_in[1];
  const float* bias = (const float*)d_in[2];
  const float* edge_weight = (const float*)d_in[3];
  const int* row = (const int*)d_in[4];
  const int* col = (const int*)d_in[5];
  float* out = (float*)d_out;
  const int E = in_sizes[3];

  char* ws = (char*)d_ws;
  float* sup = (float*)(ws + WS_SUP);

  gemm_kernel<<<N_NODES / 32, 256, 0, stream>>>(x, weight, sup);

  if (ws_size >= (size_t)WS_NEEDED) {
    int2* ebuf = (int2*)(ws + WS_EBUF);
    int* offsets = (int*)(ws + WS_OFFS);
    int* cursor = (int*)(ws + WS_CURS);
    int* counts = (int*)(ws + WS_CNTS);

    zero_counts_kernel<<<(N_NODES + 255) / 256, 256, 0, stream>>>(counts);
    hist_kernel<<<(E + 255) / 256, 256, 0, stream>>>(row, counts, E);
    scan_kernel<<<1, 1024, 0, stream>>>(counts, offsets, cursor);
    fill_kernel<<<(E + 255) / 256, 256, 0, stream>>>(row, col, edge_weight,
                                                     cursor, ebuf, E);
    gather_kernel<<<(N_NODES * 64) / 256, 256, 0, stream>>>(sup, ebuf, offsets,
                                                            bias, out);
  } else {
    bias_init_kernel<<<(N_NODES * OUT_F / 4) / 256, 256, 0, stream>>>(out, bias);
    scatter_kernel<<<(int)(((long long)E * 64 + 255) / 256), 256, 0, stream>>>(
        sup, edge_weight, row, col, out, E);
  }
}

// Round 3
// 553.438 us; speedup vs baseline: 2.7995x; 1.4742x over previous
//
#include <hip/hip_runtime.h>

#define N_NODES 100000
#define IN_F 256
#define OUT_F 128
#define NB_SCAN ((N_NODES + 255) / 256)   // 391 scan blocks

// ---------------------------------------------------------------------------
// ws layout (bytes):
//   sup     [         0,  51,200,000)  float  [N, OUT_F]
//   ebuf    [51,200,000,  64,000,000)  int2   [E]  {col, bits(edge_weight)}
//     --- transient aliases at head of ebuf (all dead before fill writes) ---
//     bswz  [ebuf+0,      ebuf+65,536)   bf16  pre-swizzled W fragments
//     bsum  [ebuf+65,536, ebuf+67,104)   int   [NB_SCAN] block sums
//     bpref [ebuf+69,632, ebuf+71,200)   int   [NB_SCAN] block prefixes
//   offsets [64,000,000,  64,400,004)  int    [N+1]
//   cursor  [64,400,008,  64,800,008)  int    [N]
//   counts  [64,800,016,  65,200,016)  int    [N]
// ---------------------------------------------------------------------------
#define WS_SUP 0
#define WS_EBUF 51200000
#define WS_OFFS 64000000
#define WS_CURS 64400008
#define WS_CNTS 64800016
#define WS_NEEDED 65200016

typedef __attribute__((ext_vector_type(8))) short short8;
typedef __attribute__((ext_vector_type(4))) float f32x4;

__device__ __forceinline__ short f2bf(float f) {
  unsigned u = __float_as_uint(f);
  unsigned r = (u + 0x7fffu + ((u >> 16) & 1u)) >> 16;   // RNE
  return (short)r;
}

// ---------------------------------------------------------------------------
// Pre-swizzle W into per-lane MFMA B-fragment layout:
// bswz[((ks*8+nt)*64+lane)*8 + j] = bf16(W[(ks*32 + (lane>>4)*8 + j)][nt*16 + (lane&15)])
// ---------------------------------------------------------------------------
__global__ __launch_bounds__(256) void prep_bswz_kernel(
    const float* __restrict__ w, short* __restrict__ bswz) {
  const int tid = blockIdx.x * 256 + threadIdx.x;   // 0..32767
  const int j = tid & 7;
  const int lane = (tid >> 3) & 63;
  const int nt = (tid >> 9) & 7;
  const int ks = tid >> 12;
  const int k = ks * 32 + ((lane >> 4) * 8) + j;
  const int n = nt * 16 + (lane & 15);
  bswz[tid] = f2bf(w[k * OUT_F + n]);
}

// ---------------------------------------------------------------------------
// support = x @ W via bf16 MFMA (16x16x32). Block = 4 waves, 64 rows.
// Wave w: rows [blk*64 + w*16, +16), all 128 cols (8 n-tiles).
// A frags loaded straight from x (fp32->bf16 in-flight), B frags from bswz.
// ---------------------------------------------------------------------------
__global__ __launch_bounds__(256) void gemm_mfma_kernel(
    const float* __restrict__ x, const short* __restrict__ bswz,
    float* __restrict__ sup) {
  const int w = threadIdx.x >> 6;
  const int lane = threadIdx.x & 63;
  const int quad = lane >> 4;
  const int m16 = lane & 15;

  const int row = blockIdx.x * 64 + w * 16 + m16;
  const int rc = row < N_NODES ? row : N_NODES - 1;   // clamp; store guarded
  const float* ap = x + (long long)rc * IN_F + quad * 8;
  const short8* bbase = (const short8*)bswz + lane;   // + (ks*8+nt)*64

  f32x4 acc[8];
#pragma unroll
  for (int nt = 0; nt < 8; ++nt) acc[nt] = (f32x4){0.f, 0.f, 0.f, 0.f};

#pragma unroll
  for (int ks = 0; ks < 8; ++ks) {
    const float4 a0 = *(const float4*)(ap + ks * 32);
    const float4 a1 = *(const float4*)(ap + ks * 32 + 4);
    short8 af;
    af[0] = f2bf(a0.x); af[1] = f2bf(a0.y); af[2] = f2bf(a0.z); af[3] = f2bf(a0.w);
    af[4] = f2bf(a1.x); af[5] = f2bf(a1.y); af[6] = f2bf(a1.z); af[7] = f2bf(a1.w);
#pragma unroll
    for (int nt = 0; nt < 8; ++nt) {
      const short8 bf = bbase[(ks * 8 + nt) * 64];
      acc[nt] = __builtin_amdgcn_mfma_f32_16x16x32_bf16(af, bf, acc[nt], 0, 0, 0);
    }
  }

  // D layout: col = lane&15, row(within 16x16) = quad*4 + reg
  const int rowbase = blockIdx.x * 64 + w * 16 + quad * 4;
#pragma unroll
  for (int nt = 0; nt < 8; ++nt) {
#pragma unroll
    for (int r = 0; r < 4; ++r) {
      const int gr = rowbase + r;
      if (gr < N_NODES) sup[(long long)gr * OUT_F + nt * 16 + m16] = acc[nt][r];
    }
  }
}

// ---------------------------------------------------------------------------
// CSR build: zero -> histogram -> hierarchical scan (3 kernels) -> fill
// ---------------------------------------------------------------------------
__global__ __launch_bounds__(256) void zero_counts_kernel(int* __restrict__ counts) {
  const int i = blockIdx.x * 256 + threadIdx.x;
  if (i < N_NODES) counts[i] = 0;
}

__global__ __launch_bounds__(256) void hist_kernel(
    const int* __restrict__ row, int* __restrict__ counts, int E) {
  const int e = blockIdx.x * 256 + threadIdx.x;
  if (e < E) atomicAdd(&counts[row[e]], 1);
}

__global__ __launch_bounds__(256) void reduce_kernel(
    const int* __restrict__ counts, int* __restrict__ bsum) {
  __shared__ int s[256];
  const int t = threadIdx.x;
  const int i = blockIdx.x * 256 + t;
  s[t] = (i < N_NODES) ? counts[i] : 0;
  __syncthreads();
#pragma unroll
  for (int off = 128; off > 0; off >>= 1) {
    if (t < off) s[t] += s[t + off];
    __syncthreads();
  }
  if (t == 0) bsum[blockIdx.x] = s[0];
}

__global__ __launch_bounds__(512) void scanb_kernel(
    const int* __restrict__ bsum, int* __restrict__ bpref,
    int* __restrict__ offsets) {
  __shared__ int s[512];
  const int t = threadIdx.x;
  const int v = (t < NB_SCAN) ? bsum[t] : 0;
  s[t] = v;
  __syncthreads();
  for (int off = 1; off < 512; off <<= 1) {
    const int w = (t >= off) ? s[t - off] : 0;
    __syncthreads();
    s[t] += w;
    __syncthreads();
  }
  if (t < NB_SCAN) bpref[t] = s[t] - v;       // exclusive
  if (t == NB_SCAN - 1) offsets[N_NODES] = s[t];
}

__global__ __launch_bounds__(256) void scan_final_kernel(
    const int* __restrict__ counts, const int* __restrict__ bpref,
    int* __restrict__ offsets, int* __restrict__ cursor) {
  __shared__ int s[256];
  const int t = threadIdx.x;
  const int i = blockIdx.x * 256 + t;
  const int v = (i < N_NODES) ? counts[i] : 0;
  s[t] = v;
  __syncthreads();
  for (int off = 1; off < 256; off <<= 1) {
    const int w = (t >= off) ? s[t - off] : 0;
    __syncthreads();
    s[t] += w;
    __syncthreads();
  }
  const int e = bpref[blockIdx.x] + s[t] - v;  // exclusive within grid
  if (i < N_NODES) {
    offsets[i] = e;
    cursor[i] = e;
  }
}

__global__ __launch_bounds__(256) void fill_kernel(
    const int* __restrict__ row, const int* __restrict__ col,
    const float* __restrict__ ew, int* __restrict__ cursor,
    int2* __restrict__ ebuf, int E) {
  const int e = blockIdx.x * 256 + threadIdx.x;
  if (e >= E) return;
  const int pos = atomicAdd(&cursor[row[e]], 1);
  ebuf[pos] = make_int2(col[e], __float_as_int(ew[e]));
}

// ---------------------------------------------------------------------------
// Gather: one wave per destination node, 2 features/lane, no atomics.
// ---------------------------------------------------------------------------
__global__ __launch_bounds__(256) void gather_kernel(
    const float* __restrict__ sup, const int2* __restrict__ ebuf,
    const int* __restrict__ offsets, const float* __restrict__ bias,
    float* __restrict__ out) {
  const int wave = (int)((blockIdx.x * 256 + threadIdx.x) >> 6);
  const int lane = threadIdx.x & 63;
  if (wave >= N_NODES) return;

  const int start = offsets[wave];
  const int end = offsets[wave + 1];

  float a0 = 0.f, a1 = 0.f;
  for (int j = start; j < end; ++j) {
    const int2 e = ebuf[j];
    const float w = __int_as_float(e.y);
    const float2 s = *(const float2*)(sup + (long long)e.x * OUT_F + lane * 2);
    a0 = fmaf(s.x, w, a0);
    a1 = fmaf(s.y, w, a1);
  }
  const float2 b = *(const float2*)(bias + lane * 2);
  *(float2*)(out + (long long)wave * OUT_F + lane * 2) =
      make_float2(a0 + b.x, a1 + b.y);
}

// ---------------------------------------------------------------------------
// Fallback (ws too small for CSR path): bias init + atomic scatter
// ---------------------------------------------------------------------------
__global__ __launch_bounds__(256) void bias_init_kernel(
    float* __restrict__ out, const float* __restrict__ bias) {
  const int t = blockIdx.x * blockDim.x + threadIdx.x;
  const int idx = t * 4;
  *(float4*)(out + idx) = *(const float4*)(bias + (idx & (OUT_F - 1)));
}

__global__ __launch_bounds__(256) void scatter_kernel(
    const float* __restrict__ sup, const float* __restrict__ ew,
    const int* __restrict__ row, const int* __restrict__ col,
    float* __restrict__ out, int E) {
  const long long t = (long long)blockIdx.x * blockDim.x + threadIdx.x;
  const int e = (int)(t >> 6);
  if (e >= E) return;
  const int lane = (int)(t & 63);
  const int c = col[e];
  const int r = row[e];
  const float wv = ew[e];
  const float2 s = *(const float2*)(sup + (long long)c * OUT_F + lane * 2);
  float* o = out + (long long)r * OUT_F + lane * 2;
  atomicAdd(o, s.x * wv);
  atomicAdd(o + 1, s.y * wv);
}

extern "C" void kernel_launch(void* const* d_in, const int* in_sizes, int n_in,
                              void* d_out, int out_size, void* d_ws, size_t ws_size,
                              hipStream_t stream) {
  const float* x = (const float*)d_in[0];
  const float* weight = (const float*)d_in[1];
  const float* bias = (const float*)d_in[2];
  const float* edge_weight = (const float*)d_in[3];
  const int* row = (const int*)d_in[4];
  const int* col = (const int*)d_in[5];
  float* out = (float*)d_out;
  const int E = in_sizes[3];

  char* ws = (char*)d_ws;
  float* sup = (float*)(ws + WS_SUP);
  short* bswz = (short*)(ws + WS_EBUF);            // transient, dies before fill
  int* bsum = (int*)(ws + WS_EBUF + 65536);        // transient
  int* bpref = (int*)(ws + WS_EBUF + 69632);       // transient

  prep_bswz_kernel<<<128, 256, 0, stream>>>(weight, bswz);
  gemm_mfma_kernel<<<(N_NODES + 63) / 64, 256, 0, stream>>>(x, bswz, sup);

  if (ws_size >= (size_t)WS_NEEDED) {
    int2* ebuf = (int2*)(ws + WS_EBUF);
    int* offsets = (int*)(ws + WS_OFFS);
    int* cursor = (int*)(ws + WS_CURS);
    int* counts = (int*)(ws + WS_CNTS);

    zero_counts_kernel<<<NB_SCAN, 256, 0, stream>>>(counts);
    hist_kernel<<<(E + 255) / 256, 256, 0, stream>>>(row, counts, E);
    reduce_kernel<<<NB_SCAN, 256, 0, stream>>>(counts, bsum);
    scanb_kernel<<<1, 512, 0, stream>>>(bsum, bpref, offsets);
    scan_final_kernel<<<NB_SCAN, 256, 0, stream>>>(counts, bpref, offsets, cursor);
    fill_kernel<<<(E + 255) / 256, 256, 0, stream>>>(row, col, edge_weight,
                                                     cursor, ebuf, E);
    gather_kernel<<<(N_NODES * 64) / 256, 256, 0, stream>>>(sup, ebuf, offsets,
                                                            bias, out);
  } else {
    bias_init_kernel<<<(N_NODES * OUT_F / 4) / 256, 256, 0, stream>>>(out, bias);
    scatter_kernel<<<(int)(((long long)E * 64 + 255) / 256), 256, 0, stream>>>(
        sup, edge_weight, row, col, out, E);
  }
}

// Round 5
// 471.055 us; speedup vs baseline: 3.2891x; 1.1749x over previous
//
#include <hip/hip_runtime.h>

#define N_NODES 100000
#define IN_F 256
#define OUT_F 128
#define NB_SCAN ((N_NODES + 255) / 256)   // 391 scan blocks

// ---------------------------------------------------------------------------
// ws layout (bytes):
//   supb    [         0,  25,600,000)  bf16   [N, OUT_F]   (ushort)
//   ebuf    [51,200,000,  64,000,000)  int2   [E]  {col, bits(edge_weight)}
//     --- transient aliases at head of ebuf (dead before fill writes) ---
//     bswz  [ebuf+0,      ebuf+65,536)   bf16  pre-swizzled W fragments
//     bsum  [ebuf+65,536, ebuf+67,104)   int   [NB_SCAN] block sums
//     bpref [ebuf+69,632, ebuf+71,200)   int   [NB_SCAN] block prefixes
//   offsets [64,000,000,  64,400,004)  int    [N+1]
//   cursor  [64,400,008,  64,800,008)  int    [N]
//   counts  [64,800,016,  65,200,016)  int    [N]  (16B aligned)
// ---------------------------------------------------------------------------
#define WS_SUP 0
#define WS_EBUF 51200000
#define WS_OFFS 64000000
#define WS_CURS 64400008
#define WS_CNTS 64800016
#define WS_NEEDED 65200016

typedef __attribute__((ext_vector_type(8))) short short8;
typedef __attribute__((ext_vector_type(4))) float f32x4;
typedef __attribute__((ext_vector_type(2))) float f32x2;

__device__ __forceinline__ unsigned short f2bf(float f) {
  unsigned u = __float_as_uint(f);
  unsigned r = (u + 0x7fffu + ((u >> 16) & 1u)) >> 16;   // RNE
  return (unsigned short)r;
}

// ---------------------------------------------------------------------------
// Pre-swizzle W into per-lane MFMA B-fragment layout.
// ---------------------------------------------------------------------------
__global__ __launch_bounds__(256) void prep_bswz_kernel(
    const float* __restrict__ w, unsigned short* __restrict__ bswz) {
  const int tid = blockIdx.x * 256 + threadIdx.x;   // 0..32767
  const int j = tid & 7;
  const int lane = (tid >> 3) & 63;
  const int nt = (tid >> 9) & 7;
  const int ks = tid >> 12;
  const int k = ks * 32 + ((lane >> 4) * 8) + j;
  const int n = nt * 16 + (lane & 15);
  bswz[tid] = f2bf(w[k * OUT_F + n]);
}

// ---------------------------------------------------------------------------
// support = x @ W via bf16 MFMA (16x16x32); output stored as bf16.
// Block = 4 waves, 64 rows; wave w: rows [blk*64+w*16, +16), all 128 cols.
// ---------------------------------------------------------------------------
__global__ __launch_bounds__(256) void gemm_mfma_kernel(
    const float* __restrict__ x, const unsigned short* __restrict__ bswz,
    unsigned short* __restrict__ supb) {
  const int w = threadIdx.x >> 6;
  const int lane = threadIdx.x & 63;
  const int quad = lane >> 4;
  const int m16 = lane & 15;

  const int row = blockIdx.x * 64 + w * 16 + m16;
  const int rc = row < N_NODES ? row : N_NODES - 1;   // clamp; store guarded
  const float* ap = x + (long long)rc * IN_F + quad * 8;
  const short8* bbase = (const short8*)bswz + lane;

  f32x4 acc[8];
#pragma unroll
  for (int nt = 0; nt < 8; ++nt) acc[nt] = (f32x4){0.f, 0.f, 0.f, 0.f};

#pragma unroll
  for (int ks = 0; ks < 8; ++ks) {
    const float4 a0 = *(const float4*)(ap + ks * 32);
    const float4 a1 = *(const float4*)(ap + ks * 32 + 4);
    short8 af;
    af[0] = f2bf(a0.x); af[1] = f2bf(a0.y); af[2] = f2bf(a0.z); af[3] = f2bf(a0.w);
    af[4] = f2bf(a1.x); af[5] = f2bf(a1.y); af[6] = f2bf(a1.z); af[7] = f2bf(a1.w);
#pragma unroll
    for (int nt = 0; nt < 8; ++nt) {
      const short8 bf = bbase[(ks * 8 + nt) * 64];
      acc[nt] = __builtin_amdgcn_mfma_f32_16x16x32_bf16(af, bf, acc[nt], 0, 0, 0);
    }
  }

  // D layout: col = lane&15, row(within tile) = quad*4 + reg
  const int rowbase = blockIdx.x * 64 + w * 16 + quad * 4;
#pragma unroll
  for (int nt = 0; nt < 8; ++nt) {
#pragma unroll
    for (int r = 0; r < 4; ++r) {
      const int gr = rowbase + r;
      if (gr < N_NODES)
        supb[(long long)gr * OUT_F + nt * 16 + m16] = f2bf(acc[nt][r]);
    }
  }
}

// ---------------------------------------------------------------------------
// CSR build: zero -> histogram -> reduce -> scan partials -> rescan -> fill
// ---------------------------------------------------------------------------
__global__ __launch_bounds__(256) void zero_counts_kernel(int4* __restrict__ counts4) {
  const int i = blockIdx.x * 256 + threadIdx.x;
  if (i < N_NODES / 4) counts4[i] = make_int4(0, 0, 0, 0);
}

__global__ __launch_bounds__(256) void hist_kernel(
    const int* __restrict__ row, int* __restrict__ counts, int E) {
  const int e0 = (blockIdx.x * 256 + threadIdx.x) * 4;
  if (e0 >= E) return;
  if (e0 + 4 <= E) {
    const int4 r = *(const int4*)(row + e0);
    atomicAdd(&counts[r.x], 1);
    atomicAdd(&counts[r.y], 1);
    atomicAdd(&counts[r.z], 1);
    atomicAdd(&counts[r.w], 1);
  } else {
    for (int e = e0; e < E; ++e) atomicAdd(&counts[row[e]], 1);
  }
}

__global__ __launch_bounds__(256) void reduce_kernel(
    const int* __restrict__ counts, int* __restrict__ bsum) {
  __shared__ int s[256];
  const int t = threadIdx.x;
  const int i = blockIdx.x * 256 + t;
  s[t] = (i < N_NODES) ? counts[i] : 0;
  __syncthreads();
#pragma unroll
  for (int off = 128; off > 0; off >>= 1) {
    if (t < off) s[t] += s[t + off];
    __syncthreads();
  }
  if (t == 0) bsum[blockIdx.x] = s[0];
}

__global__ __launch_bounds__(512) void scanb_kernel(
    const int* __restrict__ bsum, int* __restrict__ bpref,
    int* __restrict__ offsets) {
  __shared__ int s[512];
  const int t = threadIdx.x;
  const int v = (t < NB_SCAN) ? bsum[t] : 0;
  s[t] = v;
  __syncthreads();
  for (int off = 1; off < 512; off <<= 1) {
    const int w = (t >= off) ? s[t - off] : 0;
    __syncthreads();
    s[t] += w;
    __syncthreads();
  }
  if (t < NB_SCAN) bpref[t] = s[t] - v;       // exclusive
  if (t == NB_SCAN - 1) offsets[N_NODES] = s[t];
}

__global__ __launch_bounds__(256) void scan_final_kernel(
    const int* __restrict__ counts, const int* __restrict__ bpref,
    int* __restrict__ offsets, int* __restrict__ cursor) {
  __shared__ int s[256];
  const int t = threadIdx.x;
  const int i = blockIdx.x * 256 + t;
  const int v = (i < N_NODES) ? counts[i] : 0;
  s[t] = v;
  __syncthreads();
  for (int off = 1; off < 256; off <<= 1) {
    const int w = (t >= off) ? s[t - off] : 0;
    __syncthreads();
    s[t] += w;
    __syncthreads();
  }
  const int e = bpref[blockIdx.x] + s[t] - v;  // exclusive within grid
  if (i < N_NODES) {
    offsets[i] = e;
    cursor[i] = e;
  }
}

__global__ __launch_bounds__(256) void fill_kernel(
    const int* __restrict__ row, const int* __restrict__ col,
    const float* __restrict__ ew, int* __restrict__ cursor,
    int2* __restrict__ ebuf, int E) {
  const int e0 = (blockIdx.x * 256 + threadIdx.x) * 4;
  if (e0 >= E) return;
  if (e0 + 4 <= E) {
    const int4 r = *(const int4*)(row + e0);
    const int4 c = *(const int4*)(col + e0);
    const float4 wv = *(const float4*)(ew + e0);
    int p;
    p = atomicAdd(&cursor[r.x], 1); ebuf[p] = make_int2(c.x, __float_as_int(wv.x));
    p = atomicAdd(&cursor[r.y], 1); ebuf[p] = make_int2(c.y, __float_as_int(wv.y));
    p = atomicAdd(&cursor[r.z], 1); ebuf[p] = make_int2(c.z, __float_as_int(wv.z));
    p = atomicAdd(&cursor[r.w], 1); ebuf[p] = make_int2(c.w, __float_as_int(wv.w));
  } else {
    for (int e = e0; e < E; ++e) {
      const int p = atomicAdd(&cursor[row[e]], 1);
      ebuf[p] = make_int2(col[e], __float_as_int(ew[e]));
    }
  }
}

// ---------------------------------------------------------------------------
// Gather: one wave per dest node, 2 features/lane (bf16x2 load), no atomics.
// 2-edge unroll for memory-level parallelism; nontemporal out store.
// ---------------------------------------------------------------------------
__global__ __launch_bounds__(256) void gather_kernel(
    const unsigned short* __restrict__ supb, const int2* __restrict__ ebuf,
    const int* __restrict__ offsets, const float* __restrict__ bias,
    float* __restrict__ out) {
  const int wave = (int)((blockIdx.x * 256 + threadIdx.x) >> 6);
  const int lane = threadIdx.x & 63;
  if (wave >= N_NODES) return;

  const int start = offsets[wave];
  const int end = offsets[wave + 1];

  float a0 = 0.f, a1 = 0.f, b0 = 0.f, b1 = 0.f;
  int j = start;
  for (; j + 2 <= end; j += 2) {
    const int2 e0 = ebuf[j];
    const int2 e1 = ebuf[j + 1];
    const unsigned u0 = *(const unsigned*)(supb + (long long)e0.x * OUT_F + lane * 2);
    const unsigned u1 = *(const unsigned*)(supb + (long long)e1.x * OUT_F + lane * 2);
    const float w0 = __int_as_float(e0.y);
    const float w1 = __int_as_float(e1.y);
    a0 = fmaf(__uint_as_float(u0 << 16), w0, a0);
    a1 = fmaf(__uint_as_float(u0 & 0xffff0000u), w0, a1);
    b0 = fmaf(__uint_as_float(u1 << 16), w1, b0);
    b1 = fmaf(__uint_as_float(u1 & 0xffff0000u), w1, b1);
  }
  if (j < end) {
    const int2 e0 = ebuf[j];
    const unsigned u0 = *(const unsigned*)(supb + (long long)e0.x * OUT_F + lane * 2);
    const float w0 = __int_as_float(e0.y);
    a0 = fmaf(__uint_as_float(u0 << 16), w0, a0);
    a1 = fmaf(__uint_as_float(u0 & 0xffff0000u), w0, a1);
  }
  const float2 b = *(const float2*)(bias + lane * 2);
  const f32x2 v = {a0 + b0 + b.x, a1 + b1 + b.y};
  __builtin_nontemporal_store(v, (f32x2*)(out + (long long)wave * OUT_F + lane * 2));
}

// ---------------------------------------------------------------------------
// Fallback (ws too small for CSR path): bias init + atomic scatter
// ---------------------------------------------------------------------------
__global__ __launch_bounds__(256) void bias_init_kernel(
    float* __restrict__ out, const float* __restrict__ bias) {
  const int t = blockIdx.x * blockDim.x + threadIdx.x;
  const int idx = t * 4;
  *(float4*)(out + idx) = *(const float4*)(bias + (idx & (OUT_F - 1)));
}

__global__ __launch_bounds__(256) void scatter_kernel(
    const unsigned short* __restrict__ supb, const float* __restrict__ ew,
    const int* __restrict__ row, const int* __restrict__ col,
    float* __restrict__ out, int E) {
  const long long t = (long long)blockIdx.x * blockDim.x + threadIdx.x;
  const int e = (int)(t >> 6);
  if (e >= E) return;
  const int lane = (int)(t & 63);
  const int c = col[e];
  const int r = row[e];
  const float wv = ew[e];
  const unsigned u = *(const unsigned*)(supb + (long long)c * OUT_F + lane * 2);
  float* o = out + (long long)r * OUT_F + lane * 2;
  atomicAdd(o, __uint_as_float(u << 16) * wv);
  atomicAdd(o + 1, __uint_as_float(u & 0xffff0000u) * wv);
}

extern "C" void kernel_launch(void* const* d_in, const int* in_sizes, int n_in,
                              void* d_out, int out_size, void* d_ws, size_t ws_size,
                              hipStream_t stream) {
  const float* x = (const float*)d_in[0];
  const float* weight = (const float*)d_in[1];
  const float* bias = (const float*)d_in[2];
  const float* edge_weight = (const float*)d_in[3];
  const int* row = (const int*)d_in[4];
  const int* col = (const int*)d_in[5];
  float* out = (float*)d_out;
  const int E = in_sizes[3];

  char* ws = (char*)d_ws;
  unsigned short* supb = (unsigned short*)(ws + WS_SUP);
  unsigned short* bswz = (unsigned short*)(ws + WS_EBUF);  // transient
  int* bsum = (int*)(ws + WS_EBUF + 65536);                // transient
  int* bpref = (int*)(ws + WS_EBUF + 69632);               // transient

  prep_bswz_kernel<<<128, 256, 0, stream>>>(weight, bswz);
  gemm_mfma_kernel<<<(N_NODES + 63) / 64, 256, 0, stream>>>(x, bswz, supb);

  if (ws_size >= (size_t)WS_NEEDED) {
    int2* ebuf = (int2*)(ws + WS_EBUF);
    int* offsets = (int*)(ws + WS_OFFS);
    int* cursor = (int*)(ws + WS_CURS);
    int* counts = (int*)(ws + WS_CNTS);

    zero_counts_kernel<<<(N_NODES / 4 + 255) / 256, 256, 0, stream>>>((int4*)counts);
    hist_kernel<<<((E + 3) / 4 + 255) / 256, 256, 0, stream>>>(row, counts, E);
    reduce_kernel<<<NB_SCAN, 256, 0, stream>>>(counts, bsum);
    scanb_kernel<<<1, 512, 0, stream>>>(bsum, bpref, offsets);
    scan_final_kernel<<<NB_SCAN, 256, 0, stream>>>(counts, bpref, offsets, cursor);
    fill_kernel<<<((E + 3) / 4 + 255) / 256, 256, 0, stream>>>(row, col, edge_weight,
                                                               cursor, ebuf, E);
    gather_kernel<<<(N_NODES * 64) / 256, 256, 0, stream>>>(supb, ebuf, offsets,
                                                            bias, out);
  } else {
    bias_init_kernel<<<(N_NODES * OUT_F / 4) / 256, 256, 0, stream>>>(out, bias);
    scatter_kernel<<<(int)(((long long)E * 64 + 255) / 256), 256, 0, stream>>>(
        supb, edge_weight, row, col, out, E);
  }
}